// Round 14
// baseline (266.512 us; speedup 1.0000x reference)
//
#include <hip/hip_runtime.h>
#include <cstdint>
#include <math.h>

#define BB 16
#define NN 2048
#define EE 32768
#define FIN 32
#define HH 128
#define KK1 1639
#define KK2 1312
#define KK3 1050
#define PARTS 128
#define DEGC 64           // bucket capacity; P(deg>64) ~ 1e-20 for Binom(32768,1/2048)

using f16x8 = __attribute__((ext_vector_type(8))) _Float16;
using f16x2 = __attribute__((ext_vector_type(2))) _Float16;
using f32x4 = __attribute__((ext_vector_type(4))) float;

// ---------------- prep: blocks [0,2048) build layer-1 CSR; blocks [2048,..) W concat/cvt ----------------
__global__ void prep_kernel(const int* __restrict__ ei,
                            int* __restrict__ deg, int* __restrict__ csr,
                            const float* __restrict__ Wr1, const float* __restrict__ Wl1,
                            const float* __restrict__ Wr2, const float* __restrict__ Wl2,
                            const float* __restrict__ Wr3, const float* __restrict__ Wl3,
                            _Float16* __restrict__ wcat1, _Float16* __restrict__ wcat2,
                            _Float16* __restrict__ wcat3) {
    if (blockIdx.x < 2048) {
        int t = blockIdx.x * 256 + threadIdx.x;   // B*E
        int e = t & (EE - 1);
        int b = t >> 15;
        if (b >= BB) return;
        int s = ei[(size_t)b * 2 * EE + e];
        int d = ei[(size_t)b * 2 * EE + EE + e];
        int pos = atomicAdd(&deg[b * NN + d], 1);
        if (pos < DEGC) csr[((size_t)b * NN + d) * DEGC + pos] = s;
    } else {
        int idx = (blockIdx.x - 2048) * 256 + threadIdx.x;
        if (idx < 128 * 64) {
            int col = idx >> 6, k = idx & 63;
            float v = (k < FIN) ? Wr1[col * FIN + k] : Wl1[col * FIN + (k - FIN)];
            wcat1[idx] = (_Float16)v;
        } else if (idx < 128 * 64 + 128 * 256) {
            int i2 = idx - 128 * 64;
            int col = i2 >> 8, k = i2 & 255;
            float v = (k < HH) ? Wr2[col * HH + k] : Wl2[col * HH + (k - HH)];
            wcat2[i2] = (_Float16)v;
        } else {
            int i3 = idx - 128 * 64 - 128 * 256;
            if (i3 < 128 * 256) {
                int col = i3 >> 8, k = i3 & 255;
                float v = (k < HH) ? Wr3[col * HH + k] : Wl3[col * HH + (k - HH)];
                wcat3[i3] = (_Float16)v;
            }
        }
    }
}

// ---------------- f32 -> f16x8 fragment load ----------------
__device__ __forceinline__ f16x8 load_cvt16(const float* src) {
    float4 lo = *reinterpret_cast<const float4*>(src);
    float4 hi = *reinterpret_cast<const float4*>(src + 4);
    f16x8 r;
    r[0] = (_Float16)lo.x; r[1] = (_Float16)lo.y;
    r[2] = (_Float16)lo.z; r[3] = (_Float16)lo.w;
    r[4] = (_Float16)hi.x; r[5] = (_Float16)hi.y;
    r[6] = (_Float16)hi.z; r[7] = (_Float16)hi.w;
    return r;
}

// ---------------- fused agg(layer1) + MFMA conv + score; graph in bx ----------------
// Phase A: 8 groups x 32 lanes compute agg for the block's 32 rows into LDS (f16, padded).
// Phase B: 32x128 MFMA conv; agg A-fragments from LDS, x from global f32 (cvt).
__global__ __launch_bounds__(256) void convagg1_kernel(
    const float* __restrict__ x, const int* __restrict__ deg,
    const int* __restrict__ csr, const _Float16* __restrict__ wcat,
    const float* __restrict__ bias, const float* __restrict__ p,
    _Float16* __restrict__ h, unsigned long long* __restrict__ keys,
    float* __restrict__ ssc, int n) {
    __shared__ _Float16 sagg[32][40];        // 80B rows: 16B-aligned, bank-shift 20
    __shared__ float spart[4][32];
    __shared__ float snorm_s;
    int b = blockIdx.x;
    int r0 = blockIdx.y * 32;
    int t = threadIdx.x;

    if (t < 64) {
        float v = p[t] * p[t] + p[t + 64] * p[t + 64];
#pragma unroll
        for (int off = 32; off; off >>= 1) v += __shfl_xor(v, off);
        if (t == 0) snorm_s = sqrtf(v);
    }

    // ---- phase A: aggregate 32 nodes (4 per 32-lane group) ----
    {
        int g = t >> 5, lane = t & 31;
#pragma unroll
        for (int nl = 0; nl < 4; nl++) {
            int nloc = g * 4 + nl;
            int node = r0 + nloc;
            int dg = deg[b * NN + node]; if (dg > DEGC) dg = DEGC;
            const int* bucket = csr + ((size_t)b * NN + node) * DEGC;
            float acc = 0.f;
            for (int base = 0; base < dg; base += 16) {
                int m = dg - base; if (m > 16) m = 16;
                int myidx = (lane < m) ? bucket[base + lane] : 0;
                int idx[16];
#pragma unroll
                for (int u = 0; u < 16; u++) idx[u] = __shfl(myidx, u, 32);
                float v[16];
#pragma unroll
                for (int u = 0; u < 16; u++)
                    v[u] = x[((size_t)b * NN + idx[u]) * FIN + lane];
#pragma unroll
                for (int u = 0; u < 16; u++)
                    acc += (u < m) ? v[u] : 0.f;
            }
            sagg[nloc][lane] = (_Float16)acc;
        }
    }
    __syncthreads();

    // ---- phase B: MFMA conv ----
    int wv = t >> 6, lane = t & 63;
    int m16 = lane & 15, q = lane >> 4;
    f32x4 acc[2][2];
#pragma unroll
    for (int rt = 0; rt < 2; rt++)
#pragma unroll
        for (int ct = 0; ct < 2; ct++) {
            acc[rt][ct][0] = 0.f; acc[rt][ct][1] = 0.f;
            acc[rt][ct][2] = 0.f; acc[rt][ct][3] = 0.f;
        }
    int rowL[2] = { m16, 16 + m16 };
    int colB[2] = { wv * 32 + m16, wv * 32 + 16 + m16 };

#pragma unroll
    for (int step = 0; step < 2; step++) {
        int k0 = step * 32 + q * 8;
        f16x8 afr[2], bfr[2];
#pragma unroll
        for (int rt = 0; rt < 2; rt++) {
            if (k0 < FIN)
                afr[rt] = load_cvt16(x + ((size_t)b * NN + r0 + rowL[rt]) * FIN + k0);
            else
                afr[rt] = *reinterpret_cast<const f16x8*>(&sagg[rowL[rt]][k0 - FIN]);
        }
#pragma unroll
        for (int ct = 0; ct < 2; ct++)
            bfr[ct] = *reinterpret_cast<const f16x8*>(wcat + (size_t)colB[ct] * 64 + k0);
#pragma unroll
        for (int rt = 0; rt < 2; rt++)
#pragma unroll
            for (int ct = 0; ct < 2; ct++)
                acc[rt][ct] = __builtin_amdgcn_mfma_f32_16x16x32_f16(
                    afr[rt], bfr[ct], acc[rt][ct], 0, 0, 0);
    }

    float prt[2][4];
#pragma unroll
    for (int rt = 0; rt < 2; rt++)
#pragma unroll
        for (int reg = 0; reg < 4; reg++) prt[rt][reg] = 0.f;
#pragma unroll
    for (int ct = 0; ct < 2; ct++) {
        int col = wv * 32 + ct * 16 + m16;
        float pc = p[col];
        float bv = bias[col];
#pragma unroll
        for (int rt = 0; rt < 2; rt++)
#pragma unroll
            for (int reg = 0; reg < 4; reg++) {
                int row = r0 + rt * 16 + q * 4 + reg;
                float hv = fmaxf(acc[rt][ct][reg] + bv, 0.f);
                if (row < n)
                    h[((size_t)b * NN + row) * HH + col] = (_Float16)hv;
                prt[rt][reg] += hv * pc;
            }
    }
#pragma unroll
    for (int rt = 0; rt < 2; rt++)
#pragma unroll
        for (int reg = 0; reg < 4; reg++) {
            float v = prt[rt][reg];
            v += __shfl_xor(v, 1); v += __shfl_xor(v, 2);
            v += __shfl_xor(v, 4); v += __shfl_xor(v, 8);
            prt[rt][reg] = v;
        }
    if (m16 == 0) {
#pragma unroll
        for (int rt = 0; rt < 2; rt++)
#pragma unroll
            for (int reg = 0; reg < 4; reg++)
                spart[wv][rt * 16 + q * 4 + reg] = prt[rt][reg];
    }
    __syncthreads();
    if (t < 32) {
        int row = r0 + t;
        if (row < n) {
            float s = spart[0][t] + spart[1][t] + spart[2][t] + spart[3][t];
            float sc = tanhf(s / snorm_s);
            unsigned u = __float_as_uint(sc);
            u = (u & 0x80000000u) ? ~u : (u ^ 0x80000000u);
            u = ~u;
            keys[(size_t)b * NN + row] = ((unsigned long long)u << 32) | (unsigned)row;
            ssc[(size_t)b * NN + row] = sc;
        }
    }
}

// ---------------- fused agg(F=128) + MFMA conv + score; graph in bx ----------------
// Phase A: 4 waves x 8 nodes, f16x2 lanes, 16-deep gathers into LDS [32][136] f16.
// Phase B: 32x128 MFMA conv; x from global f16, agg from LDS.
__global__ __launch_bounds__(256) void convagg23_kernel(
    const _Float16* __restrict__ x, const int* __restrict__ deg,
    const int* __restrict__ csr, const _Float16* __restrict__ wcat,
    const float* __restrict__ bias, const float* __restrict__ p,
    _Float16* __restrict__ h, unsigned long long* __restrict__ keys,
    float* __restrict__ ssc, int n) {
    __shared__ _Float16 sagg[32][136];       // 272B rows: 16B-aligned, 2-way banks max
    __shared__ float spart[4][32];
    __shared__ float snorm_s;
    int b = blockIdx.x;
    int r0 = blockIdx.y * 32;
    int t = threadIdx.x;
    int wv = t >> 6, lane = t & 63;

    if (t < 64) {
        float v = p[t] * p[t] + p[t + 64] * p[t + 64];
#pragma unroll
        for (int off = 32; off; off >>= 1) v += __shfl_xor(v, off);
        if (t == 0) snorm_s = sqrtf(v);
    }

    // ---- phase A: aggregate 32 nodes (8 per wave) ----
    {
        const f16x2* xf2 = reinterpret_cast<const f16x2*>(x);
#pragma unroll
        for (int nl = 0; nl < 8; nl++) {
            int nloc = wv * 8 + nl;
            int node = r0 + nloc;
            int dg = (node < n) ? deg[b * NN + node] : 0;
            if (dg > DEGC) dg = DEGC;
            const int* bucket = csr + ((size_t)b * NN + node) * DEGC;
            float ax = 0.f, ay = 0.f;
            for (int base = 0; base < dg; base += 16) {
                int m = dg - base; if (m > 16) m = 16;
                int myidx = (lane < m) ? bucket[base + lane] : 0;
                int idx[16];
#pragma unroll
                for (int u = 0; u < 16; u++) idx[u] = __shfl(myidx, u);
                f16x2 v[16];
#pragma unroll
                for (int u = 0; u < 16; u++)
                    v[u] = xf2[((size_t)b * NN + idx[u]) * 64 + lane];
#pragma unroll
                for (int u = 0; u < 16; u++) {
                    ax += (u < m) ? (float)v[u][0] : 0.f;
                    ay += (u < m) ? (float)v[u][1] : 0.f;
                }
            }
            sagg[nloc][lane * 2]     = (_Float16)ax;
            sagg[nloc][lane * 2 + 1] = (_Float16)ay;
        }
    }
    __syncthreads();

    // ---- phase B: MFMA conv ----
    int m16 = lane & 15, q = lane >> 4;
    f32x4 acc[2][2];
#pragma unroll
    for (int rt = 0; rt < 2; rt++)
#pragma unroll
        for (int ct = 0; ct < 2; ct++) {
            acc[rt][ct][0] = 0.f; acc[rt][ct][1] = 0.f;
            acc[rt][ct][2] = 0.f; acc[rt][ct][3] = 0.f;
        }
    int rowL[2] = { m16, 16 + m16 };
    int colB[2] = { wv * 32 + m16, wv * 32 + 16 + m16 };

#pragma unroll
    for (int step = 0; step < 8; step++) {
        int k0 = step * 32 + q * 8;
        f16x8 afr[2], bfr[2];
#pragma unroll
        for (int rt = 0; rt < 2; rt++) {
            if (k0 < HH)
                afr[rt] = *reinterpret_cast<const f16x8*>(
                    x + ((size_t)b * NN + r0 + rowL[rt]) * HH + k0);
            else
                afr[rt] = *reinterpret_cast<const f16x8*>(&sagg[rowL[rt]][k0 - HH]);
        }
#pragma unroll
        for (int ct = 0; ct < 2; ct++)
            bfr[ct] = *reinterpret_cast<const f16x8*>(wcat + (size_t)colB[ct] * 256 + k0);
#pragma unroll
        for (int rt = 0; rt < 2; rt++)
#pragma unroll
            for (int ct = 0; ct < 2; ct++)
                acc[rt][ct] = __builtin_amdgcn_mfma_f32_16x16x32_f16(
                    afr[rt], bfr[ct], acc[rt][ct], 0, 0, 0);
    }

    float prt[2][4];
#pragma unroll
    for (int rt = 0; rt < 2; rt++)
#pragma unroll
        for (int reg = 0; reg < 4; reg++) prt[rt][reg] = 0.f;
#pragma unroll
    for (int ct = 0; ct < 2; ct++) {
        int col = wv * 32 + ct * 16 + m16;
        float pc = p[col];
        float bv = bias[col];
#pragma unroll
        for (int rt = 0; rt < 2; rt++)
#pragma unroll
            for (int reg = 0; reg < 4; reg++) {
                int row = r0 + rt * 16 + q * 4 + reg;
                float hv = fmaxf(acc[rt][ct][reg] + bv, 0.f);
                if (row < n)
                    h[((size_t)b * NN + row) * HH + col] = (_Float16)hv;
                prt[rt][reg] += hv * pc;
            }
    }
#pragma unroll
    for (int rt = 0; rt < 2; rt++)
#pragma unroll
        for (int reg = 0; reg < 4; reg++) {
            float v = prt[rt][reg];
            v += __shfl_xor(v, 1); v += __shfl_xor(v, 2);
            v += __shfl_xor(v, 4); v += __shfl_xor(v, 8);
            prt[rt][reg] = v;
        }
    if (m16 == 0) {
#pragma unroll
        for (int rt = 0; rt < 2; rt++)
#pragma unroll
            for (int reg = 0; reg < 4; reg++)
                spart[wv][rt * 16 + q * 4 + reg] = prt[rt][reg];
    }
    __syncthreads();
    if (t < 32) {
        int row = r0 + t;
        if (row < n) {
            float s = spart[0][t] + spart[1][t] + spart[2][t] + spart[3][t];
            float sc = tanhf(s / snorm_s);
            unsigned u = __float_as_uint(sc);
            u = (u & 0x80000000u) ? ~u : (u ^ 0x80000000u);
            u = ~u;
            keys[(size_t)b * NN + row] = ((unsigned long long)u << 32) | (unsigned)row;
            ssc[(size_t)b * NN + row] = sc;
        }
    }
}

// ---------------- exact rank; graph in bx (XCD affinity) ----------------
__global__ __launch_bounds__(256) void rank_kernel(
    const unsigned long long* __restrict__ keys, const float* __restrict__ ssc,
    int n, int k, int* __restrict__ perm, float* __restrict__ vals,
    int* __restrict__ inv) {
    __shared__ unsigned long long sk[NN];
    __shared__ int pr2[256];
    int b = blockIdx.x;
    for (int i = threadIdx.x; i < NN; i += 256)
        sk[i] = (i < n) ? keys[(size_t)b * NN + i] : ~0ULL;
    __syncthreads();
    int il = threadIdx.x & 63;
    int jg = threadIdx.x >> 6;
    int i = blockIdx.y * 64 + il;
    unsigned long long my = sk[i];
    int rank = 0;
#pragma unroll 8
    for (int j = jg * 512; j < jg * 512 + 512; j++)
        rank += (sk[j] < my) ? 1 : 0;
    pr2[threadIdx.x] = rank;
    __syncthreads();
    if (jg == 0 && i < n) {
        rank = pr2[il] + pr2[64 + il] + pr2[128 + il] + pr2[192 + il];
        if (rank < k) {
            perm[b * NN + rank] = i;
            vals[b * NN + rank] = ssc[(size_t)b * NN + i];
            inv[b * NN + i] = rank;
        } else {
            inv[b * NN + i] = -1;
        }
    }
}

// ---------------- fat kernel: [0,nbuild) edge remap+CSR build; rest gather+partials ----------------
__global__ __launch_bounds__(256) void fat_gather_build_kernel(
    int nbuild,
    const int* __restrict__ inv,
    const int* __restrict__ sin_, const int* __restrict__ din_, int in_stride,
    int* __restrict__ sout, int* __restrict__ dout, int write_next,
    int* __restrict__ deg, int* __restrict__ csr,
    const _Float16* __restrict__ hin, _Float16* __restrict__ xout,
    const int* __restrict__ perm, const float* __restrict__ vals, int k,
    float* __restrict__ part) {
    if ((int)blockIdx.x < nbuild) {
        int t = blockIdx.x * 256 + threadIdx.x;
        int e = t & (EE - 1);
        int b = t >> 15;
        if (b >= BB) return;
        int s = sin_[(size_t)b * in_stride + e];
        int d = din_[(size_t)b * in_stride + e];
        int ns = -1, nd = -1;
        if (s >= 0 && d >= 0) {
            ns = inv[b * NN + s];
            nd = inv[b * NN + d];
        }
        if (ns < 0 || nd < 0) { ns = -1; nd = -1; }
        if (write_next) {
            sout[(size_t)b * EE + e] = ns;
            dout[(size_t)b * EE + e] = nd;
        }
        if (nd >= 0) {
            int pos = atomicAdd(&deg[b * NN + nd], 1);
            if (pos < DEGC) csr[((size_t)b * NN + nd) * DEGC + pos] = ns;
        }
    } else {
        int gblk = blockIdx.x - nbuild;
        int pair = gblk * 2 + (threadIdx.x >> 7);
        int b = pair & 15;
        int j = pair >> 4;
        int f = threadIdx.x & 127;
        float mx = -INFINITY, sm = 0.f;
        int i = j;
        int pi = (i < k) ? perm[b * NN + i] : 0;
        float v = (i < k) ? vals[b * NN + i] : 0.f;
        while (i < k) {
            int inext = i + PARTS;
            int pin = 0; float vn = 0.f;
            if (inext < k) { pin = perm[b * NN + inext]; vn = vals[b * NN + inext]; }
            float hv = (float)hin[((size_t)b * NN + pi) * HH + f] * v;
            xout[((size_t)b * NN + i) * HH + f] = (_Float16)hv;
            mx = fmaxf(mx, hv);
            sm += hv;
            i = inext; pi = pin; v = vn;
        }
        part[((size_t)b * PARTS + j) * 256 + f] = mx;
        part[((size_t)b * PARTS + j) * 256 + 128 + f] = sm;
    }
}

// ---------------- final: reduce partials (3 layers x 128) + MLP ----------------
__global__ __launch_bounds__(256) void mlp_kernel(
    const float* __restrict__ partAll,
    const float* __restrict__ W1, const float* __restrict__ b1,
    const float* __restrict__ W2, const float* __restrict__ b2,
    const float* __restrict__ W3, const float* __restrict__ b3,
    float* __restrict__ out) {
    __shared__ float sg[256];
    __shared__ float s1[128];
    __shared__ float s2[64];
    int b = blockIdx.x, tid = threadIdx.x;
    const float kk[3] = {(float)KK1, (float)KK2, (float)KK3};
    float acc = 0.f;
    if (tid < 128) {
#pragma unroll
        for (int l = 0; l < 3; l++) {
            float mx = -INFINITY;
#pragma unroll 4
            for (int j = 0; j < PARTS; j++)
                mx = fmaxf(mx, partAll[(((size_t)l * BB + b) * PARTS + j) * 256 + tid]);
            acc += mx;
        }
    } else {
#pragma unroll
        for (int l = 0; l < 3; l++) {
            float sm = 0.f;
#pragma unroll 4
            for (int j = 0; j < PARTS; j++)
                sm += partAll[(((size_t)l * BB + b) * PARTS + j) * 256 + tid];
            acc += sm / kk[l];
        }
    }
    sg[tid] = acc;
    __syncthreads();
    if (tid < 128) {
        float a = b1[tid];
        for (int j = 0; j < 256; j++) a += sg[j] * W1[tid * 256 + j];
        s1[tid] = fmaxf(a, 0.f);
    }
    __syncthreads();
    if (tid < 64) {
        float a = b2[tid];
        for (int j = 0; j < 128; j++) a += s1[j] * W2[tid * 128 + j];
        s2[tid] = fmaxf(a, 0.f);
    }
    __syncthreads();
    if (tid == 0) {
        float a = b3[0];
        for (int j = 0; j < 64; j++) a += s2[j] * W3[j];
        out[b] = 1.f / (1.f + expf(-a));
    }
}

extern "C" void kernel_launch(void* const* d_in, const int* in_sizes, int n_in,
                              void* d_out, int out_size, void* d_ws, size_t ws_size,
                              hipStream_t stream) {
    const float* x   = (const float*)d_in[0];
    const int*   ei  = (const int*)d_in[1];
    const float* Wr1 = (const float*)d_in[2];
    const float* Wl1 = (const float*)d_in[3];
    const float* b1  = (const float*)d_in[4];
    const float* p1  = (const float*)d_in[5];
    const float* Wr2 = (const float*)d_in[6];
    const float* Wl2 = (const float*)d_in[7];
    const float* b2  = (const float*)d_in[8];
    const float* p2  = (const float*)d_in[9];
    const float* Wr3 = (const float*)d_in[10];
    const float* Wl3 = (const float*)d_in[11];
    const float* b3  = (const float*)d_in[12];
    const float* p3  = (const float*)d_in[13];
    const float* l1W = (const float*)d_in[14];
    const float* l1b = (const float*)d_in[15];
    const float* l2W = (const float*)d_in[16];
    const float* l2b = (const float*)d_in[17];
    const float* l3W = (const float*)d_in[18];
    const float* l3b = (const float*)d_in[19];
    float* out = (float*)d_out;

    char* ws = (char*)d_ws;
    _Float16* bufA = (_Float16*)ws; ws += (size_t)BB * NN * HH * 2;
    _Float16* bufB = (_Float16*)ws; ws += (size_t)BB * NN * HH * 2;
    int*   perm = (int*)ws;   ws += (size_t)BB * NN * 4;
    float* vals = (float*)ws; ws += (size_t)BB * NN * 4;
    int*   inv  = (int*)ws;   ws += (size_t)BB * NN * 4;
    int*   curS = (int*)ws;   ws += (size_t)BB * EE * 4;
    int*   curD = (int*)ws;   ws += (size_t)BB * EE * 4;
    float* partAll = (float*)ws; ws += (size_t)3 * BB * PARTS * 256 * 4;
    int*   deg1 = (int*)ws;   ws += (size_t)BB * NN * 4;
    int*   deg2 = (int*)ws;   ws += (size_t)BB * NN * 4;
    int*   deg3 = (int*)ws;   ws += (size_t)BB * NN * 4;
    int*   csr  = (int*)ws;   ws += (size_t)BB * NN * DEGC * 4;   // 8 MB bucketed CSR
    unsigned long long* keys = (unsigned long long*)ws; ws += (size_t)BB * NN * 8;
    float* ssc  = (float*)ws; ws += (size_t)BB * NN * 4;
    _Float16* wcat1 = (_Float16*)ws; ws += (size_t)128 * 64 * 2;
    _Float16* wcat2 = (_Float16*)ws; ws += (size_t)128 * 256 * 2;
    _Float16* wcat3 = (_Float16*)ws; ws += (size_t)128 * 256 * 2;
    float* part1 = partAll;
    float* part2 = partAll + (size_t)BB * PARTS * 256;
    float* part3 = partAll + (size_t)2 * BB * PARTS * 256;

    // one memset covers deg1/deg2/deg3 (contiguous)
    hipMemsetAsync(deg1, 0, (size_t)3 * BB * NN * 4, stream);
    // prep: build layer-1 CSR + convert/concat weights (independent, one kernel)
    hipLaunchKernelGGL(prep_kernel, dim3(2048 + (128 * 64 + 2 * 128 * 256 + 255) / 256), dim3(256), 0, stream,
                       ei, deg1, csr, Wr1, Wl1, Wr2, Wl2, Wr3, Wl3, wcat1, wcat2, wcat3);

    // ---------- layer 1 ----------
    hipLaunchKernelGGL(convagg1_kernel, dim3(BB, NN / 32), dim3(256), 0, stream,
                       x, deg1, csr, wcat1, b1, p1, bufA, keys, ssc, NN);
    hipLaunchKernelGGL(rank_kernel, dim3(BB, NN / 64), dim3(256), 0, stream, keys, ssc, NN, KK1, perm, vals, inv);
    hipLaunchKernelGGL(fat_gather_build_kernel, dim3(2048 + BB * PARTS / 2), dim3(256), 0, stream,
                       2048, inv, ei, ei + EE, 2 * EE, curS, curD, 1, deg2, csr,
                       bufA, bufB, perm, vals, KK1, part1);

    // ---------- layer 2 ----------
    hipLaunchKernelGGL(convagg23_kernel, dim3(BB, (KK1 + 31) / 32), dim3(256), 0, stream,
                       bufB, deg2, csr, wcat2, b2, p2, bufA, keys, ssc, KK1);
    hipLaunchKernelGGL(rank_kernel, dim3(BB, NN / 64), dim3(256), 0, stream, keys, ssc, KK1, KK2, perm, vals, inv);
    hipLaunchKernelGGL(fat_gather_build_kernel, dim3(2048 + BB * PARTS / 2), dim3(256), 0, stream,
                       2048, inv, curS, curD, EE, curS, curD, 0, deg3, csr,
                       bufA, bufB, perm, vals, KK2, part2);

    // ---------- layer 3 ----------
    hipLaunchKernelGGL(convagg23_kernel, dim3(BB, (KK2 + 31) / 32), dim3(256), 0, stream,
                       bufB, deg3, csr, wcat3, b3, p3, bufA, keys, ssc, KK2);
    hipLaunchKernelGGL(rank_kernel, dim3(BB, NN / 64), dim3(256), 0, stream, keys, ssc, KK2, KK3, perm, vals, inv);
    hipLaunchKernelGGL(fat_gather_build_kernel, dim3(BB * PARTS / 2), dim3(256), 0, stream,
                       0, inv, curS, curD, EE, curS, curD, 0, deg3, csr,
                       bufA, bufB, perm, vals, KK3, part3);

    // ---------- final: reduce partials + MLP ----------
    hipLaunchKernelGGL(mlp_kernel, dim3(BB), dim3(256), 0, stream,
                       partAll, l1W, l1b, l2W, l2b, l3W, l3b, out);
}

// Round 15
// 211.059 us; speedup vs baseline: 1.2627x; 1.2627x over previous
//
#include <hip/hip_runtime.h>
#include <cstdint>
#include <math.h>

#define BB 16
#define NN 2048
#define EE 32768
#define FIN 32
#define HH 128
#define KK1 1639
#define KK2 1312
#define KK3 1050
#define PARTS 128
#define PGRP 8            // combined groups per graph/layer
#define JPG (PARTS / PGRP)
#define DEGC 64           // bucket capacity; P(deg>64) ~ 1e-20 for Binom(32768,1/2048)

using f16x8 = __attribute__((ext_vector_type(8))) _Float16;
using f16x2 = __attribute__((ext_vector_type(2))) _Float16;
using f32x4 = __attribute__((ext_vector_type(4))) float;

// ---------------- prep: blocks [0,2048) build layer-1 CSR; blocks [2048,..) W concat/cvt ----------------
__global__ void prep_kernel(const int* __restrict__ ei,
                            int* __restrict__ deg, int* __restrict__ csr,
                            const float* __restrict__ Wr1, const float* __restrict__ Wl1,
                            const float* __restrict__ Wr2, const float* __restrict__ Wl2,
                            const float* __restrict__ Wr3, const float* __restrict__ Wl3,
                            _Float16* __restrict__ wcat1, _Float16* __restrict__ wcat2,
                            _Float16* __restrict__ wcat3) {
    if (blockIdx.x < 2048) {
        int t = blockIdx.x * 256 + threadIdx.x;   // B*E
        int e = t & (EE - 1);
        int b = t >> 15;
        if (b >= BB) return;
        int s = ei[(size_t)b * 2 * EE + e];
        int d = ei[(size_t)b * 2 * EE + EE + e];
        int pos = atomicAdd(&deg[b * NN + d], 1);
        if (pos < DEGC) csr[((size_t)b * NN + d) * DEGC + pos] = s;
    } else {
        int idx = (blockIdx.x - 2048) * 256 + threadIdx.x;
        if (idx < 128 * 64) {
            int col = idx >> 6, k = idx & 63;
            float v = (k < FIN) ? Wr1[col * FIN + k] : Wl1[col * FIN + (k - FIN)];
            wcat1[idx] = (_Float16)v;
        } else if (idx < 128 * 64 + 128 * 256) {
            int i2 = idx - 128 * 64;
            int col = i2 >> 8, k = i2 & 255;
            float v = (k < HH) ? Wr2[col * HH + k] : Wl2[col * HH + (k - HH)];
            wcat2[i2] = (_Float16)v;
        } else {
            int i3 = idx - 128 * 64 - 128 * 256;
            if (i3 < 128 * 256) {
                int col = i3 >> 8, k = i3 & 255;
                float v = (k < HH) ? Wr3[col * HH + k] : Wl3[col * HH + (k - HH)];
                wcat3[i3] = (_Float16)v;
            }
        }
    }
}

// ---------------- f32 -> f16x8 fragment load ----------------
__device__ __forceinline__ f16x8 load_cvt16(const float* src) {
    float4 lo = *reinterpret_cast<const float4*>(src);
    float4 hi = *reinterpret_cast<const float4*>(src + 4);
    f16x8 r;
    r[0] = (_Float16)lo.x; r[1] = (_Float16)lo.y;
    r[2] = (_Float16)lo.z; r[3] = (_Float16)lo.w;
    r[4] = (_Float16)hi.x; r[5] = (_Float16)hi.y;
    r[6] = (_Float16)hi.z; r[7] = (_Float16)hi.w;
    return r;
}

// ---------------- fused agg(layer1) + MFMA conv + score; graph in bx ----------------
__global__ __launch_bounds__(256) void convagg1_kernel(
    const float* __restrict__ x, const int* __restrict__ deg,
    const int* __restrict__ csr, const _Float16* __restrict__ wcat,
    const float* __restrict__ bias, const float* __restrict__ p,
    _Float16* __restrict__ h, unsigned long long* __restrict__ keys,
    float* __restrict__ ssc, int n) {
    __shared__ _Float16 sagg[32][40];
    __shared__ float spart[4][32];
    __shared__ float snorm_s;
    int b = blockIdx.x;
    int r0 = blockIdx.y * 32;
    int t = threadIdx.x;

    if (t < 64) {
        float v = p[t] * p[t] + p[t + 64] * p[t + 64];
#pragma unroll
        for (int off = 32; off; off >>= 1) v += __shfl_xor(v, off);
        if (t == 0) snorm_s = sqrtf(v);
    }

    // ---- phase A: aggregate 32 nodes (4 per 32-lane group) ----
    {
        int g = t >> 5, lane = t & 31;
#pragma unroll
        for (int nl = 0; nl < 4; nl++) {
            int nloc = g * 4 + nl;
            int node = r0 + nloc;
            int dg = deg[b * NN + node]; if (dg > DEGC) dg = DEGC;
            const int* bucket = csr + ((size_t)b * NN + node) * DEGC;
            float acc = 0.f;
            for (int base = 0; base < dg; base += 16) {
                int m = dg - base; if (m > 16) m = 16;
                int myidx = (lane < m) ? bucket[base + lane] : 0;
                int idx[16];
#pragma unroll
                for (int u = 0; u < 16; u++) idx[u] = __shfl(myidx, u, 32);
                float v[16];
#pragma unroll
                for (int u = 0; u < 16; u++)
                    v[u] = x[((size_t)b * NN + idx[u]) * FIN + lane];
#pragma unroll
                for (int u = 0; u < 16; u++)
                    acc += (u < m) ? v[u] : 0.f;
            }
            sagg[nloc][lane] = (_Float16)acc;
        }
    }
    __syncthreads();

    // ---- phase B: MFMA conv ----
    int wv = t >> 6, lane = t & 63;
    int m16 = lane & 15, q = lane >> 4;
    f32x4 acc[2][2];
#pragma unroll
    for (int rt = 0; rt < 2; rt++)
#pragma unroll
        for (int ct = 0; ct < 2; ct++) {
            acc[rt][ct][0] = 0.f; acc[rt][ct][1] = 0.f;
            acc[rt][ct][2] = 0.f; acc[rt][ct][3] = 0.f;
        }
    int rowL[2] = { m16, 16 + m16 };
    int colB[2] = { wv * 32 + m16, wv * 32 + 16 + m16 };

#pragma unroll
    for (int step = 0; step < 2; step++) {
        int k0 = step * 32 + q * 8;
        f16x8 afr[2], bfr[2];
#pragma unroll
        for (int rt = 0; rt < 2; rt++) {
            if (k0 < FIN)
                afr[rt] = load_cvt16(x + ((size_t)b * NN + r0 + rowL[rt]) * FIN + k0);
            else
                afr[rt] = *reinterpret_cast<const f16x8*>(&sagg[rowL[rt]][k0 - FIN]);
        }
#pragma unroll
        for (int ct = 0; ct < 2; ct++)
            bfr[ct] = *reinterpret_cast<const f16x8*>(wcat + (size_t)colB[ct] * 64 + k0);
#pragma unroll
        for (int rt = 0; rt < 2; rt++)
#pragma unroll
            for (int ct = 0; ct < 2; ct++)
                acc[rt][ct] = __builtin_amdgcn_mfma_f32_16x16x32_f16(
                    afr[rt], bfr[ct], acc[rt][ct], 0, 0, 0);
    }

    float prt[2][4];
#pragma unroll
    for (int rt = 0; rt < 2; rt++)
#pragma unroll
        for (int reg = 0; reg < 4; reg++) prt[rt][reg] = 0.f;
#pragma unroll
    for (int ct = 0; ct < 2; ct++) {
        int col = wv * 32 + ct * 16 + m16;
        float pc = p[col];
        float bv = bias[col];
#pragma unroll
        for (int rt = 0; rt < 2; rt++)
#pragma unroll
            for (int reg = 0; reg < 4; reg++) {
                int row = r0 + rt * 16 + q * 4 + reg;
                float hv = fmaxf(acc[rt][ct][reg] + bv, 0.f);
                if (row < n)
                    h[((size_t)b * NN + row) * HH + col] = (_Float16)hv;
                prt[rt][reg] += hv * pc;
            }
    }
#pragma unroll
    for (int rt = 0; rt < 2; rt++)
#pragma unroll
        for (int reg = 0; reg < 4; reg++) {
            float v = prt[rt][reg];
            v += __shfl_xor(v, 1); v += __shfl_xor(v, 2);
            v += __shfl_xor(v, 4); v += __shfl_xor(v, 8);
            prt[rt][reg] = v;
        }
    if (m16 == 0) {
#pragma unroll
        for (int rt = 0; rt < 2; rt++)
#pragma unroll
            for (int reg = 0; reg < 4; reg++)
                spart[wv][rt * 16 + q * 4 + reg] = prt[rt][reg];
    }
    __syncthreads();
    if (t < 32) {
        int row = r0 + t;
        if (row < n) {
            float s = spart[0][t] + spart[1][t] + spart[2][t] + spart[3][t];
            float sc = tanhf(s / snorm_s);
            unsigned u = __float_as_uint(sc);
            u = (u & 0x80000000u) ? ~u : (u ^ 0x80000000u);
            u = ~u;
            keys[(size_t)b * NN + row] = ((unsigned long long)u << 32) | (unsigned)row;
            ssc[(size_t)b * NN + row] = sc;
        }
    }
}

// ---------------- fused agg(F=128) + MFMA conv + score; graph in bx ----------------
__global__ __launch_bounds__(256) void convagg23_kernel(
    const _Float16* __restrict__ x, const int* __restrict__ deg,
    const int* __restrict__ csr, const _Float16* __restrict__ wcat,
    const float* __restrict__ bias, const float* __restrict__ p,
    _Float16* __restrict__ h, unsigned long long* __restrict__ keys,
    float* __restrict__ ssc, int n) {
    __shared__ _Float16 sagg[32][136];
    __shared__ float spart[4][32];
    __shared__ float snorm_s;
    int b = blockIdx.x;
    int r0 = blockIdx.y * 32;
    int t = threadIdx.x;
    int wv = t >> 6, lane = t & 63;

    if (t < 64) {
        float v = p[t] * p[t] + p[t + 64] * p[t + 64];
#pragma unroll
        for (int off = 32; off; off >>= 1) v += __shfl_xor(v, off);
        if (t == 0) snorm_s = sqrtf(v);
    }

    // ---- phase A: aggregate 32 nodes (8 per wave) ----
    {
        const f16x2* xf2 = reinterpret_cast<const f16x2*>(x);
#pragma unroll
        for (int nl = 0; nl < 8; nl++) {
            int nloc = wv * 8 + nl;
            int node = r0 + nloc;
            int dg = (node < n) ? deg[b * NN + node] : 0;
            if (dg > DEGC) dg = DEGC;
            const int* bucket = csr + ((size_t)b * NN + node) * DEGC;
            float ax = 0.f, ay = 0.f;
            for (int base = 0; base < dg; base += 16) {
                int m = dg - base; if (m > 16) m = 16;
                int myidx = (lane < m) ? bucket[base + lane] : 0;
                int idx[16];
#pragma unroll
                for (int u = 0; u < 16; u++) idx[u] = __shfl(myidx, u);
                f16x2 v[16];
#pragma unroll
                for (int u = 0; u < 16; u++)
                    v[u] = xf2[((size_t)b * NN + idx[u]) * 64 + lane];
#pragma unroll
                for (int u = 0; u < 16; u++) {
                    ax += (u < m) ? (float)v[u][0] : 0.f;
                    ay += (u < m) ? (float)v[u][1] : 0.f;
                }
            }
            sagg[nloc][lane * 2]     = (_Float16)ax;
            sagg[nloc][lane * 2 + 1] = (_Float16)ay;
        }
    }
    __syncthreads();

    // ---- phase B: MFMA conv ----
    int m16 = lane & 15, q = lane >> 4;
    f32x4 acc[2][2];
#pragma unroll
    for (int rt = 0; rt < 2; rt++)
#pragma unroll
        for (int ct = 0; ct < 2; ct++) {
            acc[rt][ct][0] = 0.f; acc[rt][ct][1] = 0.f;
            acc[rt][ct][2] = 0.f; acc[rt][ct][3] = 0.f;
        }
    int rowL[2] = { m16, 16 + m16 };
    int colB[2] = { wv * 32 + m16, wv * 32 + 16 + m16 };

#pragma unroll
    for (int step = 0; step < 8; step++) {
        int k0 = step * 32 + q * 8;
        f16x8 afr[2], bfr[2];
#pragma unroll
        for (int rt = 0; rt < 2; rt++) {
            if (k0 < HH)
                afr[rt] = *reinterpret_cast<const f16x8*>(
                    x + ((size_t)b * NN + r0 + rowL[rt]) * HH + k0);
            else
                afr[rt] = *reinterpret_cast<const f16x8*>(&sagg[rowL[rt]][k0 - HH]);
        }
#pragma unroll
        for (int ct = 0; ct < 2; ct++)
            bfr[ct] = *reinterpret_cast<const f16x8*>(wcat + (size_t)colB[ct] * 256 + k0);
#pragma unroll
        for (int rt = 0; rt < 2; rt++)
#pragma unroll
            for (int ct = 0; ct < 2; ct++)
                acc[rt][ct] = __builtin_amdgcn_mfma_f32_16x16x32_f16(
                    afr[rt], bfr[ct], acc[rt][ct], 0, 0, 0);
    }

    float prt[2][4];
#pragma unroll
    for (int rt = 0; rt < 2; rt++)
#pragma unroll
        for (int reg = 0; reg < 4; reg++) prt[rt][reg] = 0.f;
#pragma unroll
    for (int ct = 0; ct < 2; ct++) {
        int col = wv * 32 + ct * 16 + m16;
        float pc = p[col];
        float bv = bias[col];
#pragma unroll
        for (int rt = 0; rt < 2; rt++)
#pragma unroll
            for (int reg = 0; reg < 4; reg++) {
                int row = r0 + rt * 16 + q * 4 + reg;
                float hv = fmaxf(acc[rt][ct][reg] + bv, 0.f);
                if (row < n)
                    h[((size_t)b * NN + row) * HH + col] = (_Float16)hv;
                prt[rt][reg] += hv * pc;
            }
    }
#pragma unroll
    for (int rt = 0; rt < 2; rt++)
#pragma unroll
        for (int reg = 0; reg < 4; reg++) {
            float v = prt[rt][reg];
            v += __shfl_xor(v, 1); v += __shfl_xor(v, 2);
            v += __shfl_xor(v, 4); v += __shfl_xor(v, 8);
            prt[rt][reg] = v;
        }
    if (m16 == 0) {
#pragma unroll
        for (int rt = 0; rt < 2; rt++)
#pragma unroll
            for (int reg = 0; reg < 4; reg++)
                spart[wv][rt * 16 + q * 4 + reg] = prt[rt][reg];
    }
    __syncthreads();
    if (t < 32) {
        int row = r0 + t;
        if (row < n) {
            float s = spart[0][t] + spart[1][t] + spart[2][t] + spart[3][t];
            float sc = tanhf(s / snorm_s);
            unsigned u = __float_as_uint(sc);
            u = (u & 0x80000000u) ? ~u : (u ^ 0x80000000u);
            u = ~u;
            keys[(size_t)b * NN + row] = ((unsigned long long)u << 32) | (unsigned)row;
            ssc[(size_t)b * NN + row] = sc;
        }
    }
}

// ---------------- exact rank; graph in bx (XCD affinity) ----------------
__global__ __launch_bounds__(256) void rank_kernel(
    const unsigned long long* __restrict__ keys, const float* __restrict__ ssc,
    int n, int k, int* __restrict__ perm, float* __restrict__ vals,
    int* __restrict__ inv) {
    __shared__ unsigned long long sk[NN];
    __shared__ int pr2[256];
    int b = blockIdx.x;
    for (int i = threadIdx.x; i < NN; i += 256)
        sk[i] = (i < n) ? keys[(size_t)b * NN + i] : ~0ULL;
    __syncthreads();
    int il = threadIdx.x & 63;
    int jg = threadIdx.x >> 6;
    int i = blockIdx.y * 64 + il;
    unsigned long long my = sk[i];
    int rank = 0;
#pragma unroll 8
    for (int j = jg * 512; j < jg * 512 + 512; j++)
        rank += (sk[j] < my) ? 1 : 0;
    pr2[threadIdx.x] = rank;
    __syncthreads();
    if (jg == 0 && i < n) {
        rank = pr2[il] + pr2[64 + il] + pr2[128 + il] + pr2[192 + il];
        if (rank < k) {
            perm[b * NN + rank] = i;
            vals[b * NN + rank] = ssc[(size_t)b * NN + i];
            inv[b * NN + i] = rank;
        } else {
            inv[b * NN + i] = -1;
        }
    }
}

// ---------------- fat kernel: [0,nbuild) edge remap+CSR build; rest gather+partials ----------------
__global__ __launch_bounds__(256) void fat_gather_build_kernel(
    int nbuild,
    const int* __restrict__ inv,
    const int* __restrict__ sin_, const int* __restrict__ din_, int in_stride,
    int* __restrict__ sout, int* __restrict__ dout, int write_next,
    int* __restrict__ deg, int* __restrict__ csr,
    const _Float16* __restrict__ hin, _Float16* __restrict__ xout,
    const int* __restrict__ perm, const float* __restrict__ vals, int k,
    float* __restrict__ part) {
    if ((int)blockIdx.x < nbuild) {
        int t = blockIdx.x * 256 + threadIdx.x;
        int e = t & (EE - 1);
        int b = t >> 15;
        if (b >= BB) return;
        int s = sin_[(size_t)b * in_stride + e];
        int d = din_[(size_t)b * in_stride + e];
        int ns = -1, nd = -1;
        if (s >= 0 && d >= 0) {
            ns = inv[b * NN + s];
            nd = inv[b * NN + d];
        }
        if (ns < 0 || nd < 0) { ns = -1; nd = -1; }
        if (write_next) {
            sout[(size_t)b * EE + e] = ns;
            dout[(size_t)b * EE + e] = nd;
        }
        if (nd >= 0) {
            int pos = atomicAdd(&deg[b * NN + nd], 1);
            if (pos < DEGC) csr[((size_t)b * NN + nd) * DEGC + pos] = ns;
        }
    } else {
        int gblk = blockIdx.x - nbuild;
        int pair = gblk * 2 + (threadIdx.x >> 7);
        int b = pair & 15;
        int j = pair >> 4;
        int f = threadIdx.x & 127;
        float mx = -INFINITY, sm = 0.f;
        int i = j;
        int pi = (i < k) ? perm[b * NN + i] : 0;
        float v = (i < k) ? vals[b * NN + i] : 0.f;
        while (i < k) {
            int inext = i + PARTS;
            int pin = 0; float vn = 0.f;
            if (inext < k) { pin = perm[b * NN + inext]; vn = vals[b * NN + inext]; }
            float hv = (float)hin[((size_t)b * NN + pi) * HH + f] * v;
            xout[((size_t)b * NN + i) * HH + f] = (_Float16)hv;
            mx = fmaxf(mx, hv);
            sm += hv;
            i = inext; pi = pin; v = vn;
        }
        part[((size_t)b * PARTS + j) * 256 + f] = mx;
        part[((size_t)b * PARTS + j) * 256 + 128 + f] = sm;
    }
}

// ---------------- hierarchical combine: [3][BB][PARTS][256] -> [3][BB][PGRP][256] ----------------
__global__ __launch_bounds__(256) void combine_kernel(
    const float* __restrict__ partAll, float* __restrict__ partG) {
    int blk = blockIdx.x;            // l*BB*PGRP + b*PGRP + g
    int g = blk % PGRP;
    int rem = blk / PGRP;
    int b = rem & 15;
    int l = rem >> 4;
    int f = threadIdx.x;
    const float* src = partAll + ((((size_t)l * BB + b) * PARTS) + (size_t)g * JPG) * 256;
    float r;
    if (f < 128) {
        r = -INFINITY;
#pragma unroll
        for (int j = 0; j < JPG; j++) r = fmaxf(r, src[j * 256 + f]);
    } else {
        r = 0.f;
#pragma unroll
        for (int j = 0; j < JPG; j++) r += src[j * 256 + f];
    }
    partG[(((size_t)l * BB + b) * PGRP + g) * 256 + f] = r;
}

// ---------------- final: combine group partials (3 layers) + MLP ----------------
__global__ __launch_bounds__(256) void mlp_kernel(
    const float* __restrict__ partG,
    const float* __restrict__ W1, const float* __restrict__ b1,
    const float* __restrict__ W2, const float* __restrict__ b2,
    const float* __restrict__ W3, const float* __restrict__ b3,
    float* __restrict__ out) {
    __shared__ float sg[256];
    __shared__ float s1[128];
    __shared__ float s2[64];
    int b = blockIdx.x, tid = threadIdx.x;
    const float kk[3] = {(float)KK1, (float)KK2, (float)KK3};
    float acc = 0.f;
    if (tid < 128) {
#pragma unroll
        for (int l = 0; l < 3; l++) {
            float mx = -INFINITY;
#pragma unroll
            for (int j = 0; j < PGRP; j++)
                mx = fmaxf(mx, partG[(((size_t)l * BB + b) * PGRP + j) * 256 + tid]);
            acc += mx;
        }
    } else {
#pragma unroll
        for (int l = 0; l < 3; l++) {
            float sm = 0.f;
#pragma unroll
            for (int j = 0; j < PGRP; j++)
                sm += partG[(((size_t)l * BB + b) * PGRP + j) * 256 + tid];
            acc += sm / kk[l];
        }
    }
    sg[tid] = acc;
    __syncthreads();
    if (tid < 128) {
        float a = b1[tid];
        for (int j = 0; j < 256; j++) a += sg[j] * W1[tid * 256 + j];
        s1[tid] = fmaxf(a, 0.f);
    }
    __syncthreads();
    if (tid < 64) {
        float a = b2[tid];
        for (int j = 0; j < 128; j++) a += s1[j] * W2[tid * 128 + j];
        s2[tid] = fmaxf(a, 0.f);
    }
    __syncthreads();
    if (tid == 0) {
        float a = b3[0];
        for (int j = 0; j < 64; j++) a += s2[j] * W3[j];
        out[b] = 1.f / (1.f + expf(-a));
    }
}

extern "C" void kernel_launch(void* const* d_in, const int* in_sizes, int n_in,
                              void* d_out, int out_size, void* d_ws, size_t ws_size,
                              hipStream_t stream) {
    const float* x   = (const float*)d_in[0];
    const int*   ei  = (const int*)d_in[1];
    const float* Wr1 = (const float*)d_in[2];
    const float* Wl1 = (const float*)d_in[3];
    const float* b1  = (const float*)d_in[4];
    const float* p1  = (const float*)d_in[5];
    const float* Wr2 = (const float*)d_in[6];
    const float* Wl2 = (const float*)d_in[7];
    const float* b2  = (const float*)d_in[8];
    const float* p2  = (const float*)d_in[9];
    const float* Wr3 = (const float*)d_in[10];
    const float* Wl3 = (const float*)d_in[11];
    const float* b3  = (const float*)d_in[12];
    const float* p3  = (const float*)d_in[13];
    const float* l1W = (const float*)d_in[14];
    const float* l1b = (const float*)d_in[15];
    const float* l2W = (const float*)d_in[16];
    const float* l2b = (const float*)d_in[17];
    const float* l3W = (const float*)d_in[18];
    const float* l3b = (const float*)d_in[19];
    float* out = (float*)d_out;

    char* ws = (char*)d_ws;
    _Float16* bufA = (_Float16*)ws; ws += (size_t)BB * NN * HH * 2;
    _Float16* bufB = (_Float16*)ws; ws += (size_t)BB * NN * HH * 2;
    int*   perm = (int*)ws;   ws += (size_t)BB * NN * 4;
    float* vals = (float*)ws; ws += (size_t)BB * NN * 4;
    int*   inv  = (int*)ws;   ws += (size_t)BB * NN * 4;
    int*   curS = (int*)ws;   ws += (size_t)BB * EE * 4;
    int*   curD = (int*)ws;   ws += (size_t)BB * EE * 4;
    float* partAll = (float*)ws; ws += (size_t)3 * BB * PARTS * 256 * 4;
    float* partG   = (float*)ws; ws += (size_t)3 * BB * PGRP * 256 * 4;
    int*   deg1 = (int*)ws;   ws += (size_t)BB * NN * 4;
    int*   deg2 = (int*)ws;   ws += (size_t)BB * NN * 4;
    int*   deg3 = (int*)ws;   ws += (size_t)BB * NN * 4;
    int*   csr  = (int*)ws;   ws += (size_t)BB * NN * DEGC * 4;   // 8 MB bucketed CSR
    unsigned long long* keys = (unsigned long long*)ws; ws += (size_t)BB * NN * 8;
    float* ssc  = (float*)ws; ws += (size_t)BB * NN * 4;
    _Float16* wcat1 = (_Float16*)ws; ws += (size_t)128 * 64 * 2;
    _Float16* wcat2 = (_Float16*)ws; ws += (size_t)128 * 256 * 2;
    _Float16* wcat3 = (_Float16*)ws; ws += (size_t)128 * 256 * 2;
    float* part1 = partAll;
    float* part2 = partAll + (size_t)BB * PARTS * 256;
    float* part3 = partAll + (size_t)2 * BB * PARTS * 256;

    // one memset covers deg1/deg2/deg3 (contiguous)
    hipMemsetAsync(deg1, 0, (size_t)3 * BB * NN * 4, stream);
    hipLaunchKernelGGL(prep_kernel, dim3(2048 + (128 * 64 + 2 * 128 * 256 + 255) / 256), dim3(256), 0, stream,
                       ei, deg1, csr, Wr1, Wl1, Wr2, Wl2, Wr3, Wl3, wcat1, wcat2, wcat3);

    // ---------- layer 1 ----------
    hipLaunchKernelGGL(convagg1_kernel, dim3(BB, NN / 32), dim3(256), 0, stream,
                       x, deg1, csr, wcat1, b1, p1, bufA, keys, ssc, NN);
    hipLaunchKernelGGL(rank_kernel, dim3(BB, NN / 64), dim3(256), 0, stream, keys, ssc, NN, KK1, perm, vals, inv);
    hipLaunchKernelGGL(fat_gather_build_kernel, dim3(2048 + BB * PARTS / 2), dim3(256), 0, stream,
                       2048, inv, ei, ei + EE, 2 * EE, curS, curD, 1, deg2, csr,
                       bufA, bufB, perm, vals, KK1, part1);

    // ---------- layer 2 ----------
    hipLaunchKernelGGL(convagg23_kernel, dim3(BB, (KK1 + 31) / 32), dim3(256), 0, stream,
                       bufB, deg2, csr, wcat2, b2, p2, bufA, keys, ssc, KK1);
    hipLaunchKernelGGL(rank_kernel, dim3(BB, NN / 64), dim3(256), 0, stream, keys, ssc, KK1, KK2, perm, vals, inv);
    hipLaunchKernelGGL(fat_gather_build_kernel, dim3(2048 + BB * PARTS / 2), dim3(256), 0, stream,
                       2048, inv, curS, curD, EE, curS, curD, 0, deg3, csr,
                       bufA, bufB, perm, vals, KK2, part2);

    // ---------- layer 3 ----------
    hipLaunchKernelGGL(convagg23_kernel, dim3(BB, (KK2 + 31) / 32), dim3(256), 0, stream,
                       bufB, deg3, csr, wcat3, b3, p3, bufA, keys, ssc, KK2);
    hipLaunchKernelGGL(rank_kernel, dim3(BB, NN / 64), dim3(256), 0, stream, keys, ssc, KK2, KK3, perm, vals, inv);
    hipLaunchKernelGGL(fat_gather_build_kernel, dim3(BB * PARTS / 2), dim3(256), 0, stream,
                       0, inv, curS, curD, EE, curS, curD, 0, deg3, csr,
                       bufA, bufB, perm, vals, KK3, part3);

    // ---------- final: hierarchical combine + MLP ----------
    hipLaunchKernelGGL(combine_kernel, dim3(3 * BB * PGRP), dim3(256), 0, stream, partAll, partG);
    hipLaunchKernelGGL(mlp_kernel, dim3(BB), dim3(256), 0, stream,
                       partG, l1W, l1b, l2W, l2b, l3W, l3b, out);
}

// Round 16
// 204.814 us; speedup vs baseline: 1.3012x; 1.0305x over previous
//
#include <hip/hip_runtime.h>
#include <cstdint>
#include <math.h>

#define BB 16
#define NN 2048
#define EE 32768
#define FIN 32
#define HH 128
#define KK1 1639
#define KK2 1312
#define KK3 1050
#define PARTS 128
#define PGRP 8            // combined groups per graph/layer
#define JPG (PARTS / PGRP)
#define DEGC 64           // bucket capacity; P(deg>64) ~ 1e-20 for Binom(32768,1/2048)

using f16x8 = __attribute__((ext_vector_type(8))) _Float16;
using f16x4 = __attribute__((ext_vector_type(4))) _Float16;
using f16x2 = __attribute__((ext_vector_type(2))) _Float16;
using f32x4 = __attribute__((ext_vector_type(4))) float;

// ---------------- prep: blocks [0,2048) build layer-1 CSR; blocks [2048,..) W concat/cvt ----------------
__global__ void prep_kernel(const int* __restrict__ ei,
                            int* __restrict__ deg, int* __restrict__ csr,
                            const float* __restrict__ Wr1, const float* __restrict__ Wl1,
                            const float* __restrict__ Wr2, const float* __restrict__ Wl2,
                            const float* __restrict__ Wr3, const float* __restrict__ Wl3,
                            _Float16* __restrict__ wcat1, _Float16* __restrict__ wcat2,
                            _Float16* __restrict__ wcat3) {
    if (blockIdx.x < 2048) {
        int t = blockIdx.x * 256 + threadIdx.x;   // B*E
        int e = t & (EE - 1);
        int b = t >> 15;
        if (b >= BB) return;
        int s = ei[(size_t)b * 2 * EE + e];
        int d = ei[(size_t)b * 2 * EE + EE + e];
        int pos = atomicAdd(&deg[b * NN + d], 1);
        if (pos < DEGC) csr[((size_t)b * NN + d) * DEGC + pos] = s;
    } else {
        int idx = (blockIdx.x - 2048) * 256 + threadIdx.x;
        if (idx < 128 * 64) {
            int col = idx >> 6, k = idx & 63;
            float v = (k < FIN) ? Wr1[col * FIN + k] : Wl1[col * FIN + (k - FIN)];
            wcat1[idx] = (_Float16)v;
        } else if (idx < 128 * 64 + 128 * 256) {
            int i2 = idx - 128 * 64;
            int col = i2 >> 8, k = i2 & 255;
            float v = (k < HH) ? Wr2[col * HH + k] : Wl2[col * HH + (k - HH)];
            wcat2[i2] = (_Float16)v;
        } else {
            int i3 = idx - 128 * 64 - 128 * 256;
            if (i3 < 128 * 256) {
                int col = i3 >> 8, k = i3 & 255;
                float v = (k < HH) ? Wr3[col * HH + k] : Wl3[col * HH + (k - HH)];
                wcat3[i3] = (_Float16)v;
            }
        }
    }
}

// ---------------- f32 -> f16x8 fragment load ----------------
__device__ __forceinline__ f16x8 load_cvt16(const float* src) {
    float4 lo = *reinterpret_cast<const float4*>(src);
    float4 hi = *reinterpret_cast<const float4*>(src + 4);
    f16x8 r;
    r[0] = (_Float16)lo.x; r[1] = (_Float16)lo.y;
    r[2] = (_Float16)lo.z; r[3] = (_Float16)lo.w;
    r[4] = (_Float16)hi.x; r[5] = (_Float16)hi.y;
    r[6] = (_Float16)hi.z; r[7] = (_Float16)hi.w;
    return r;
}

// ---------------- fused agg(layer1) + MFMA conv + score; graph in bx ----------------
__global__ __launch_bounds__(256) void convagg1_kernel(
    const float* __restrict__ x, const int* __restrict__ deg,
    const int* __restrict__ csr, const _Float16* __restrict__ wcat,
    const float* __restrict__ bias, const float* __restrict__ p,
    _Float16* __restrict__ h, unsigned long long* __restrict__ keys,
    float* __restrict__ ssc, int n) {
    __shared__ _Float16 sagg[32][40];
    __shared__ float spart[4][32];
    __shared__ float snorm_s;
    int b = blockIdx.x;
    int r0 = blockIdx.y * 32;
    int t = threadIdx.x;

    if (t < 64) {
        float v = p[t] * p[t] + p[t + 64] * p[t + 64];
#pragma unroll
        for (int off = 32; off; off >>= 1) v += __shfl_xor(v, off);
        if (t == 0) snorm_s = sqrtf(v);
    }

    // ---- phase A: aggregate 32 nodes (4 per 32-lane group) ----
    {
        int g = t >> 5, lane = t & 31;
#pragma unroll
        for (int nl = 0; nl < 4; nl++) {
            int nloc = g * 4 + nl;
            int node = r0 + nloc;
            int dg = deg[b * NN + node]; if (dg > DEGC) dg = DEGC;
            const int* bucket = csr + ((size_t)b * NN + node) * DEGC;
            float acc = 0.f;
            for (int base = 0; base < dg; base += 16) {
                int m = dg - base; if (m > 16) m = 16;
                int myidx = (lane < m) ? bucket[base + lane] : 0;
                int idx[16];
#pragma unroll
                for (int u = 0; u < 16; u++) idx[u] = __shfl(myidx, u, 32);
                float v[16];
#pragma unroll
                for (int u = 0; u < 16; u++)
                    v[u] = x[((size_t)b * NN + idx[u]) * FIN + lane];
#pragma unroll
                for (int u = 0; u < 16; u++)
                    acc += (u < m) ? v[u] : 0.f;
            }
            sagg[nloc][lane] = (_Float16)acc;
        }
    }
    __syncthreads();

    // ---- phase B: MFMA conv ----
    int wv = t >> 6, lane = t & 63;
    int m16 = lane & 15, q = lane >> 4;
    f32x4 acc[2][2];
#pragma unroll
    for (int rt = 0; rt < 2; rt++)
#pragma unroll
        for (int ct = 0; ct < 2; ct++) {
            acc[rt][ct][0] = 0.f; acc[rt][ct][1] = 0.f;
            acc[rt][ct][2] = 0.f; acc[rt][ct][3] = 0.f;
        }
    int rowL[2] = { m16, 16 + m16 };
    int colB[2] = { wv * 32 + m16, wv * 32 + 16 + m16 };

#pragma unroll
    for (int step = 0; step < 2; step++) {
        int k0 = step * 32 + q * 8;
        f16x8 afr[2], bfr[2];
#pragma unroll
        for (int rt = 0; rt < 2; rt++) {
            if (k0 < FIN)
                afr[rt] = load_cvt16(x + ((size_t)b * NN + r0 + rowL[rt]) * FIN + k0);
            else
                afr[rt] = *reinterpret_cast<const f16x8*>(&sagg[rowL[rt]][k0 - FIN]);
        }
#pragma unroll
        for (int ct = 0; ct < 2; ct++)
            bfr[ct] = *reinterpret_cast<const f16x8*>(wcat + (size_t)colB[ct] * 64 + k0);
#pragma unroll
        for (int rt = 0; rt < 2; rt++)
#pragma unroll
            for (int ct = 0; ct < 2; ct++)
                acc[rt][ct] = __builtin_amdgcn_mfma_f32_16x16x32_f16(
                    afr[rt], bfr[ct], acc[rt][ct], 0, 0, 0);
    }

    float prt[2][4];
#pragma unroll
    for (int rt = 0; rt < 2; rt++)
#pragma unroll
        for (int reg = 0; reg < 4; reg++) prt[rt][reg] = 0.f;
#pragma unroll
    for (int ct = 0; ct < 2; ct++) {
        int col = wv * 32 + ct * 16 + m16;
        float pc = p[col];
        float bv = bias[col];
#pragma unroll
        for (int rt = 0; rt < 2; rt++)
#pragma unroll
            for (int reg = 0; reg < 4; reg++) {
                int row = r0 + rt * 16 + q * 4 + reg;
                float hv = fmaxf(acc[rt][ct][reg] + bv, 0.f);
                if (row < n)
                    h[((size_t)b * NN + row) * HH + col] = (_Float16)hv;
                prt[rt][reg] += hv * pc;
            }
    }
#pragma unroll
    for (int rt = 0; rt < 2; rt++)
#pragma unroll
        for (int reg = 0; reg < 4; reg++) {
            float v = prt[rt][reg];
            v += __shfl_xor(v, 1); v += __shfl_xor(v, 2);
            v += __shfl_xor(v, 4); v += __shfl_xor(v, 8);
            prt[rt][reg] = v;
        }
    if (m16 == 0) {
#pragma unroll
        for (int rt = 0; rt < 2; rt++)
#pragma unroll
            for (int reg = 0; reg < 4; reg++)
                spart[wv][rt * 16 + q * 4 + reg] = prt[rt][reg];
    }
    __syncthreads();
    if (t < 32) {
        int row = r0 + t;
        if (row < n) {
            float s = spart[0][t] + spart[1][t] + spart[2][t] + spart[3][t];
            float sc = tanhf(s / snorm_s);
            unsigned u = __float_as_uint(sc);
            u = (u & 0x80000000u) ? ~u : (u ^ 0x80000000u);
            u = ~u;
            keys[(size_t)b * NN + row] = ((unsigned long long)u << 32) | (unsigned)row;
            ssc[(size_t)b * NN + row] = sc;
        }
    }
}

// ---------------- fused agg(F=128) + MFMA conv + score; graph in bx ----------------
// Phase A: 8x 32-lane groups, each owning a node (f16x4 lanes, 16-deep) -> 8 nodes in flight.
__global__ __launch_bounds__(256) void convagg23_kernel(
    const _Float16* __restrict__ x, const int* __restrict__ deg,
    const int* __restrict__ csr, const _Float16* __restrict__ wcat,
    const float* __restrict__ bias, const float* __restrict__ p,
    _Float16* __restrict__ h, unsigned long long* __restrict__ keys,
    float* __restrict__ ssc, int n) {
    __shared__ _Float16 sagg[32][136];
    __shared__ float spart[4][32];
    __shared__ float snorm_s;
    int b = blockIdx.x;
    int r0 = blockIdx.y * 32;
    int t = threadIdx.x;

    if (t < 64) {
        float v = p[t] * p[t] + p[t + 64] * p[t + 64];
#pragma unroll
        for (int off = 32; off; off >>= 1) v += __shfl_xor(v, off);
        if (t == 0) snorm_s = sqrtf(v);
    }

    // ---- phase A: aggregate 32 nodes (4 per 32-lane group; 8 groups in flight) ----
    {
        int g32 = t >> 5, l32 = t & 31;
        const f16x4* xf4 = reinterpret_cast<const f16x4*>(x);
#pragma unroll
        for (int nl = 0; nl < 4; nl++) {
            int nloc = g32 * 4 + nl;
            int node = r0 + nloc;
            int dg = (node < n) ? deg[b * NN + node] : 0;
            if (dg > DEGC) dg = DEGC;
            const int* bucket = csr + ((size_t)b * NN + node) * DEGC;
            float a0 = 0.f, a1 = 0.f, a2 = 0.f, a3 = 0.f;
            for (int base = 0; base < dg; base += 16) {
                int m = dg - base; if (m > 16) m = 16;
                int myidx = (l32 < m) ? bucket[base + l32] : 0;
                int idx[16];
#pragma unroll
                for (int u = 0; u < 16; u++) idx[u] = __shfl(myidx, u, 32);
                f16x4 v[16];
#pragma unroll
                for (int u = 0; u < 16; u++)
                    v[u] = xf4[((size_t)b * NN + idx[u]) * 32 + l32];
#pragma unroll
                for (int u = 0; u < 16; u++) {
                    a0 += (u < m) ? (float)v[u][0] : 0.f;
                    a1 += (u < m) ? (float)v[u][1] : 0.f;
                    a2 += (u < m) ? (float)v[u][2] : 0.f;
                    a3 += (u < m) ? (float)v[u][3] : 0.f;
                }
            }
            f16x4 o; o[0] = (_Float16)a0; o[1] = (_Float16)a1;
            o[2] = (_Float16)a2; o[3] = (_Float16)a3;
            *reinterpret_cast<f16x4*>(&sagg[nloc][l32 * 4]) = o;
        }
    }
    __syncthreads();

    // ---- phase B: MFMA conv ----
    int wv = t >> 6, lane = t & 63;
    int m16 = lane & 15, q = lane >> 4;
    f32x4 acc[2][2];
#pragma unroll
    for (int rt = 0; rt < 2; rt++)
#pragma unroll
        for (int ct = 0; ct < 2; ct++) {
            acc[rt][ct][0] = 0.f; acc[rt][ct][1] = 0.f;
            acc[rt][ct][2] = 0.f; acc[rt][ct][3] = 0.f;
        }
    int rowL[2] = { m16, 16 + m16 };
    int colB[2] = { wv * 32 + m16, wv * 32 + 16 + m16 };

#pragma unroll
    for (int step = 0; step < 8; step++) {
        int k0 = step * 32 + q * 8;
        f16x8 afr[2], bfr[2];
#pragma unroll
        for (int rt = 0; rt < 2; rt++) {
            if (k0 < HH)
                afr[rt] = *reinterpret_cast<const f16x8*>(
                    x + ((size_t)b * NN + r0 + rowL[rt]) * HH + k0);
            else
                afr[rt] = *reinterpret_cast<const f16x8*>(&sagg[rowL[rt]][k0 - HH]);
        }
#pragma unroll
        for (int ct = 0; ct < 2; ct++)
            bfr[ct] = *reinterpret_cast<const f16x8*>(wcat + (size_t)colB[ct] * 256 + k0);
#pragma unroll
        for (int rt = 0; rt < 2; rt++)
#pragma unroll
            for (int ct = 0; ct < 2; ct++)
                acc[rt][ct] = __builtin_amdgcn_mfma_f32_16x16x32_f16(
                    afr[rt], bfr[ct], acc[rt][ct], 0, 0, 0);
    }

    float prt[2][4];
#pragma unroll
    for (int rt = 0; rt < 2; rt++)
#pragma unroll
        for (int reg = 0; reg < 4; reg++) prt[rt][reg] = 0.f;
#pragma unroll
    for (int ct = 0; ct < 2; ct++) {
        int col = wv * 32 + ct * 16 + m16;
        float pc = p[col];
        float bv = bias[col];
#pragma unroll
        for (int rt = 0; rt < 2; rt++)
#pragma unroll
            for (int reg = 0; reg < 4; reg++) {
                int row = r0 + rt * 16 + q * 4 + reg;
                float hv = fmaxf(acc[rt][ct][reg] + bv, 0.f);
                if (row < n)
                    h[((size_t)b * NN + row) * HH + col] = (_Float16)hv;
                prt[rt][reg] += hv * pc;
            }
    }
#pragma unroll
    for (int rt = 0; rt < 2; rt++)
#pragma unroll
        for (int reg = 0; reg < 4; reg++) {
            float v = prt[rt][reg];
            v += __shfl_xor(v, 1); v += __shfl_xor(v, 2);
            v += __shfl_xor(v, 4); v += __shfl_xor(v, 8);
            prt[rt][reg] = v;
        }
    if (m16 == 0) {
#pragma unroll
        for (int rt = 0; rt < 2; rt++)
#pragma unroll
            for (int reg = 0; reg < 4; reg++)
                spart[wv][rt * 16 + q * 4 + reg] = prt[rt][reg];
    }
    __syncthreads();
    if (t < 32) {
        int row = r0 + t;
        if (row < n) {
            float s = spart[0][t] + spart[1][t] + spart[2][t] + spart[3][t];
            float sc = tanhf(s / snorm_s);
            unsigned u = __float_as_uint(sc);
            u = (u & 0x80000000u) ? ~u : (u ^ 0x80000000u);
            u = ~u;
            keys[(size_t)b * NN + row] = ((unsigned long long)u << 32) | (unsigned)row;
            ssc[(size_t)b * NN + row] = sc;
        }
    }
}

// ---------------- exact rank; graph in bx (XCD affinity) ----------------
__global__ __launch_bounds__(256) void rank_kernel(
    const unsigned long long* __restrict__ keys, const float* __restrict__ ssc,
    int n, int k, int* __restrict__ perm, float* __restrict__ vals,
    int* __restrict__ inv) {
    __shared__ unsigned long long sk[NN];
    __shared__ int pr2[256];
    int b = blockIdx.x;
    for (int i = threadIdx.x; i < NN; i += 256)
        sk[i] = (i < n) ? keys[(size_t)b * NN + i] : ~0ULL;
    __syncthreads();
    int il = threadIdx.x & 63;
    int jg = threadIdx.x >> 6;
    int i = blockIdx.y * 64 + il;
    unsigned long long my = sk[i];
    int rank = 0;
#pragma unroll 8
    for (int j = jg * 512; j < jg * 512 + 512; j++)
        rank += (sk[j] < my) ? 1 : 0;
    pr2[threadIdx.x] = rank;
    __syncthreads();
    if (jg == 0 && i < n) {
        rank = pr2[il] + pr2[64 + il] + pr2[128 + il] + pr2[192 + il];
        if (rank < k) {
            perm[b * NN + rank] = i;
            vals[b * NN + rank] = ssc[(size_t)b * NN + i];
            inv[b * NN + i] = rank;
        } else {
            inv[b * NN + i] = -1;
        }
    }
}

// ---------------- fat kernel: [0,nbuild) edge remap+CSR build; rest gather+partials ----------------
__global__ __launch_bounds__(256) void fat_gather_build_kernel(
    int nbuild,
    const int* __restrict__ inv,
    const int* __restrict__ sin_, const int* __restrict__ din_, int in_stride,
    int* __restrict__ sout, int* __restrict__ dout, int write_next,
    int* __restrict__ deg, int* __restrict__ csr,
    const _Float16* __restrict__ hin, _Float16* __restrict__ xout,
    const int* __restrict__ perm, const float* __restrict__ vals, int k,
    float* __restrict__ part) {
    if ((int)blockIdx.x < nbuild) {
        int t = blockIdx.x * 256 + threadIdx.x;
        int e = t & (EE - 1);
        int b = t >> 15;
        if (b >= BB) return;
        int s = sin_[(size_t)b * in_stride + e];
        int d = din_[(size_t)b * in_stride + e];
        int ns = -1, nd = -1;
        if (s >= 0 && d >= 0) {
            ns = inv[b * NN + s];
            nd = inv[b * NN + d];
        }
        if (ns < 0 || nd < 0) { ns = -1; nd = -1; }
        if (write_next) {
            sout[(size_t)b * EE + e] = ns;
            dout[(size_t)b * EE + e] = nd;
        }
        if (nd >= 0) {
            int pos = atomicAdd(&deg[b * NN + nd], 1);
            if (pos < DEGC) csr[((size_t)b * NN + nd) * DEGC + pos] = ns;
        }
    } else {
        int gblk = blockIdx.x - nbuild;
        int pair = gblk * 2 + (threadIdx.x >> 7);
        int b = pair & 15;
        int j = pair >> 4;
        int f = threadIdx.x & 127;
        float mx = -INFINITY, sm = 0.f;
        int i = j;
        int pi = (i < k) ? perm[b * NN + i] : 0;
        float v = (i < k) ? vals[b * NN + i] : 0.f;
        while (i < k) {
            int inext = i + PARTS;
            int pin = 0; float vn = 0.f;
            if (inext < k) { pin = perm[b * NN + inext]; vn = vals[b * NN + inext]; }
            float hv = (float)hin[((size_t)b * NN + pi) * HH + f] * v;
            xout[((size_t)b * NN + i) * HH + f] = (_Float16)hv;
            mx = fmaxf(mx, hv);
            sm += hv;
            i = inext; pi = pin; v = vn;
        }
        part[((size_t)b * PARTS + j) * 256 + f] = mx;
        part[((size_t)b * PARTS + j) * 256 + 128 + f] = sm;
    }
}

// ---------------- hierarchical combine: [3][BB][PARTS][256] -> [3][BB][PGRP][256] ----------------
__global__ __launch_bounds__(256) void combine_kernel(
    const float* __restrict__ partAll, float* __restrict__ partG) {
    int blk = blockIdx.x;            // l*BB*PGRP + b*PGRP + g
    int g = blk % PGRP;
    int rem = blk / PGRP;
    int b = rem & 15;
    int l = rem >> 4;
    int f = threadIdx.x;
    const float* src = partAll + ((((size_t)l * BB + b) * PARTS) + (size_t)g * JPG) * 256;
    float r;
    if (f < 128) {
        r = -INFINITY;
#pragma unroll
        for (int j = 0; j < JPG; j++) r = fmaxf(r, src[j * 256 + f]);
    } else {
        r = 0.f;
#pragma unroll
        for (int j = 0; j < JPG; j++) r += src[j * 256 + f];
    }
    partG[(((size_t)l * BB + b) * PGRP + g) * 256 + f] = r;
}

// ---------------- final: combine group partials (3 layers) + MLP ----------------
__global__ __launch_bounds__(256) void mlp_kernel(
    const float* __restrict__ partG,
    const float* __restrict__ W1, const float* __restrict__ b1,
    const float* __restrict__ W2, const float* __restrict__ b2,
    const float* __restrict__ W3, const float* __restrict__ b3,
    float* __restrict__ out) {
    __shared__ float sg[256];
    __shared__ float s1[128];
    __shared__ float s2[64];
    int b = blockIdx.x, tid = threadIdx.x;
    const float kk[3] = {(float)KK1, (float)KK2, (float)KK3};
    float acc = 0.f;
    if (tid < 128) {
#pragma unroll
        for (int l = 0; l < 3; l++) {
            float mx = -INFINITY;
#pragma unroll
            for (int j = 0; j < PGRP; j++)
                mx = fmaxf(mx, partG[(((size_t)l * BB + b) * PGRP + j) * 256 + tid]);
            acc += mx;
        }
    } else {
#pragma unroll
        for (int l = 0; l < 3; l++) {
            float sm = 0.f;
#pragma unroll
            for (int j = 0; j < PGRP; j++)
                sm += partG[(((size_t)l * BB + b) * PGRP + j) * 256 + tid];
            acc += sm / kk[l];
        }
    }
    sg[tid] = acc;
    __syncthreads();
    if (tid < 128) {
        float a = b1[tid];
        for (int j = 0; j < 256; j++) a += sg[j] * W1[tid * 256 + j];
        s1[tid] = fmaxf(a, 0.f);
    }
    __syncthreads();
    if (tid < 64) {
        float a = b2[tid];
        for (int j = 0; j < 128; j++) a += s1[j] * W2[tid * 128 + j];
        s2[tid] = fmaxf(a, 0.f);
    }
    __syncthreads();
    if (tid == 0) {
        float a = b3[0];
        for (int j = 0; j < 64; j++) a += s2[j] * W3[j];
        out[b] = 1.f / (1.f + expf(-a));
    }
}

extern "C" void kernel_launch(void* const* d_in, const int* in_sizes, int n_in,
                              void* d_out, int out_size, void* d_ws, size_t ws_size,
                              hipStream_t stream) {
    const float* x   = (const float*)d_in[0];
    const int*   ei  = (const int*)d_in[1];
    const float* Wr1 = (const float*)d_in[2];
    const float* Wl1 = (const float*)d_in[3];
    const float* b1  = (const float*)d_in[4];
    const float* p1  = (const float*)d_in[5];
    const float* Wr2 = (const float*)d_in[6];
    const float* Wl2 = (const float*)d_in[7];
    const float* b2  = (const float*)d_in[8];
    const float* p2  = (const float*)d_in[9];
    const float* Wr3 = (const float*)d_in[10];
    const float* Wl3 = (const float*)d_in[11];
    const float* b3  = (const float*)d_in[12];
    const float* p3  = (const float*)d_in[13];
    const float* l1W = (const float*)d_in[14];
    const float* l1b = (const float*)d_in[15];
    const float* l2W = (const float*)d_in[16];
    const float* l2b = (const float*)d_in[17];
    const float* l3W = (const float*)d_in[18];
    const float* l3b = (const float*)d_in[19];
    float* out = (float*)d_out;

    char* ws = (char*)d_ws;
    _Float16* bufA = (_Float16*)ws; ws += (size_t)BB * NN * HH * 2;
    _Float16* bufB = (_Float16*)ws; ws += (size_t)BB * NN * HH * 2;
    int*   perm = (int*)ws;   ws += (size_t)BB * NN * 4;
    float* vals = (float*)ws; ws += (size_t)BB * NN * 4;
    int*   inv  = (int*)ws;   ws += (size_t)BB * NN * 4;
    int*   curS = (int*)ws;   ws += (size_t)BB * EE * 4;
    int*   curD = (int*)ws;   ws += (size_t)BB * EE * 4;
    float* partAll = (float*)ws; ws += (size_t)3 * BB * PARTS * 256 * 4;
    float* partG   = (float*)ws; ws += (size_t)3 * BB * PGRP * 256 * 4;
    int*   deg1 = (int*)ws;   ws += (size_t)BB * NN * 4;
    int*   deg2 = (int*)ws;   ws += (size_t)BB * NN * 4;
    int*   deg3 = (int*)ws;   ws += (size_t)BB * NN * 4;
    int*   csr  = (int*)ws;   ws += (size_t)BB * NN * DEGC * 4;   // 8 MB bucketed CSR
    unsigned long long* keys = (unsigned long long*)ws; ws += (size_t)BB * NN * 8;
    float* ssc  = (float*)ws; ws += (size_t)BB * NN * 4;
    _Float16* wcat1 = (_Float16*)ws; ws += (size_t)128 * 64 * 2;
    _Float16* wcat2 = (_Float16*)ws; ws += (size_t)128 * 256 * 2;
    _Float16* wcat3 = (_Float16*)ws; ws += (size_t)128 * 256 * 2;
    float* part1 = partAll;
    float* part2 = partAll + (size_t)BB * PARTS * 256;
    float* part3 = partAll + (size_t)2 * BB * PARTS * 256;

    // one memset covers deg1/deg2/deg3 (contiguous)
    hipMemsetAsync(deg1, 0, (size_t)3 * BB * NN * 4, stream);
    hipLaunchKernelGGL(prep_kernel, dim3(2048 + (128 * 64 + 2 * 128 * 256 + 255) / 256), dim3(256), 0, stream,
                       ei, deg1, csr, Wr1, Wl1, Wr2, Wl2, Wr3, Wl3, wcat1, wcat2, wcat3);

    // ---------- layer 1 ----------
    hipLaunchKernelGGL(convagg1_kernel, dim3(BB, NN / 32), dim3(256), 0, stream,
                       x, deg1, csr, wcat1, b1, p1, bufA, keys, ssc, NN);
    hipLaunchKernelGGL(rank_kernel, dim3(BB, NN / 64), dim3(256), 0, stream, keys, ssc, NN, KK1, perm, vals, inv);
    hipLaunchKernelGGL(fat_gather_build_kernel, dim3(2048 + BB * PARTS / 2), dim3(256), 0, stream,
                       2048, inv, ei, ei + EE, 2 * EE, curS, curD, 1, deg2, csr,
                       bufA, bufB, perm, vals, KK1, part1);

    // ---------- layer 2 ----------
    hipLaunchKernelGGL(convagg23_kernel, dim3(BB, (KK1 + 31) / 32), dim3(256), 0, stream,
                       bufB, deg2, csr, wcat2, b2, p2, bufA, keys, ssc, KK1);
    hipLaunchKernelGGL(rank_kernel, dim3(BB, NN / 64), dim3(256), 0, stream, keys, ssc, KK1, KK2, perm, vals, inv);
    hipLaunchKernelGGL(fat_gather_build_kernel, dim3(2048 + BB * PARTS / 2), dim3(256), 0, stream,
                       2048, inv, curS, curD, EE, curS, curD, 0, deg3, csr,
                       bufA, bufB, perm, vals, KK2, part2);

    // ---------- layer 3 ----------
    hipLaunchKernelGGL(convagg23_kernel, dim3(BB, (KK2 + 31) / 32), dim3(256), 0, stream,
                       bufB, deg3, csr, wcat3, b3, p3, bufA, keys, ssc, KK2);
    hipLaunchKernelGGL(rank_kernel, dim3(BB, NN / 64), dim3(256), 0, stream, keys, ssc, KK2, KK3, perm, vals, inv);
    hipLaunchKernelGGL(fat_gather_build_kernel, dim3(BB * PARTS / 2), dim3(256), 0, stream,
                       0, inv, curS, curD, EE, curS, curD, 0, deg3, csr,
                       bufA, bufB, perm, vals, KK3, part3);

    // ---------- final: hierarchical combine + MLP ----------
    hipLaunchKernelGGL(combine_kernel, dim3(3 * BB * PGRP), dim3(256), 0, stream, partAll, partG);
    hipLaunchKernelGGL(mlp_kernel, dim3(BB), dim3(256), 0, stream,
                       partG, l1W, l1b, l2W, l2b, l3W, l3b, out);
}